// Round 13
// baseline (47.086 us; speedup 1.0000x reference)
//
#include <hip/hip_runtime.h>
#include <math.h>

// DTM layer: B=32, N=1024, D=2, M0=0.05, R=2
// out = sqrt( (A_strict(t*) + t*(wb - S_strict(t*)))/wb ), t* = weighted
// 5%-quantile of d2, wb = 0.05*sum_b(w).
// R11 = R10 structure (round-trip minimal) + tail fixes:
//  - seed t0 = 0.1*pi*exp(min(r2/2, 3)): the Gaussian small-t model explodes
//    for far queries (r2>6); capped seed ~6.3 sits inside the true tail
//    quantile range (|x|-r_c)^2 in [1,9]  -> ladder brackets tails too.
//  - ladder {0.5, 1.2, 2.88}*t0 (S-only, fused into pass0 with wsum+max);
//  - 4 adaptive refinements (S-only scans, one DPP chain each);
//  - one fused two-sided epilogue pass for A at lo,hi; concave-envelope
//    output (val(t) concave piecewise-linear, max at t*; tangent-intersection
//    estimate is exact when <=1 point inside the final bracket).
// Dependent round-trips: 6 (R8: ~8).

constexpr int   PER_LANE = 16;     // 1024 / 64
constexpr float M0_      = 0.05f;

template<int CTRL, int RM>
__device__ __forceinline__ float dpp_fadd(float v) {
    int moved = __builtin_amdgcn_update_dpp(0, __float_as_int(v), CTRL, RM, 0xF, true);
    return v + __int_as_float(moved);
}
template<int CTRL, int RM>
__device__ __forceinline__ float dpp_fmax(float v) {
    int moved = __builtin_amdgcn_update_dpp(0, __float_as_int(v), CTRL, RM, 0xF, true);
    return fmaxf(v, __int_as_float(moved));
}
__device__ __forceinline__ float lane63(float v) {
    return __uint_as_float((unsigned)__builtin_amdgcn_readlane(__float_as_int(v), 63));
}

// 4 interleaved sum chains + 1 max chain, one latency depth
__device__ __forceinline__ void wave_red5(float& a, float& b, float& c,
                                          float& d, float& m) {
#define STG(CT, RM) \
    a = dpp_fadd<CT,RM>(a); b = dpp_fadd<CT,RM>(b); c = dpp_fadd<CT,RM>(c); \
    d = dpp_fadd<CT,RM>(d); m = dpp_fmax<CT,RM>(m);
    STG(0x111,0xF) STG(0x112,0xF) STG(0x114,0xF)
    STG(0x118,0xF) STG(0x142,0xA) STG(0x143,0xC)
#undef STG
    a = lane63(a); b = lane63(b); c = lane63(c); d = lane63(d); m = lane63(m);
}
__device__ __forceinline__ float wave_sum1(float v) {
    v = dpp_fadd<0x111,0xF>(v); v = dpp_fadd<0x112,0xF>(v);
    v = dpp_fadd<0x114,0xF>(v); v = dpp_fadd<0x118,0xF>(v);
    v = dpp_fadd<0x142,0xA>(v); v = dpp_fadd<0x143,0xC>(v);
    return lane63(v);
}
__device__ __forceinline__ void wave_sum2_u(float& a, float& b) {
    a = dpp_fadd<0x111,0xF>(a); b = dpp_fadd<0x111,0xF>(b);
    a = dpp_fadd<0x112,0xF>(a); b = dpp_fadd<0x112,0xF>(b);
    a = dpp_fadd<0x114,0xF>(a); b = dpp_fadd<0x114,0xF>(b);
    a = dpp_fadd<0x118,0xF>(a); b = dpp_fadd<0x118,0xF>(b);
    a = dpp_fadd<0x142,0xA>(a); b = dpp_fadd<0x142,0xA>(b);
    a = dpp_fadd<0x143,0xC>(a); b = dpp_fadd<0x143,0xC>(b);
    a = lane63(a); b = lane63(b);
}

__global__ __launch_bounds__(256) void dtm_kernel(
    const float* __restrict__ input,   // [B, N, 2]
    const float* __restrict__ weight,  // [B, N]
    const float* __restrict__ grid,    // [N, 2]
    float* __restrict__ out)           // [B, N]
{
    const int wave = threadIdx.x >> 6;
    const int lane = threadIdx.x & 63;
    const int q    = (blockIdx.x << 2) + wave;
    const int b    = q >> 10;

    const float2 xq = reinterpret_cast<const float2*>(input)[q];

    // capped analytic seed (tail-safe): t0 <= 0.314*e^3 ~ 6.3
    const float r2q = xq.x * xq.x + xq.y * xq.y;
    const float t0  = 0.31415927f * __expf(fminf(0.5f * r2q, 3.0f));
    const float t1  = 0.50f * t0, t2 = 1.20f * t0, t3 = 2.88f * t0;

    const int base = lane * PER_LANE;
    const float4* w4 = reinterpret_cast<const float4*>(weight + (b << 10) + base);
    const float4* g4 = reinterpret_cast<const float4*>(grid + 2 * base);

    float w[PER_LANE], d2[PER_LANE];
    float wsum = 0.f;
    #pragma unroll
    for (int i = 0; i < 4; ++i) {
        const float4 x = w4[i];
        w[4*i+0] = x.x; w[4*i+1] = x.y; w[4*i+2] = x.z; w[4*i+3] = x.w;
        wsum += x.x + x.y + x.z + x.w;
    }

    // ---- pass0: d2 + 3 S-only ladder probes + max, fused; ONE reduction
    float S1 = 0.f, S2 = 0.f, S3 = 0.f, mx = 0.f;
    #pragma unroll
    for (int i = 0; i < 8; ++i) {                   // 2 grid points per float4
        const float4 g = g4[i];
        #pragma unroll
        for (int j = 0; j < 2; ++j) {
            const int k  = 2*i + j;
            const float gx = j ? g.z : g.x;
            const float gy = j ? g.w : g.y;
            const float dx = xq.x - gx, dy = xq.y - gy;
            const float dk = dx * dx + dy * dy;
            d2[k] = dk;
            const float wk = w[k];
            mx = fmaxf(mx, dk);
            S1 += (dk <= t1) ? wk : 0.f;
            S2 += (dk <= t2) ? wk : 0.f;
            S3 += (dk <= t3) ? wk : 0.f;
        }
    }
    wave_red5(wsum, S1, S2, S3, mx);                // round-trip 1
    const float total = wsum;
    const float wb    = M0_ * total;

    // ---- init bracket from ladder (wave-uniform scalars)
    float lo, Wlo, hi, Whi;
    bool hiP;                                        // hi probed (Whi real)?
    if (S1 >= wb)      { lo = 0.f; Wlo = 0.f; hi = t1; Whi = S1;    hiP = true;  }
    else if (S2 >= wb) { lo = t1;  Wlo = S1;  hi = t2; Whi = S2;    hiP = true;  }
    else if (S3 >= wb) { lo = t2;  Wlo = S2;  hi = t3; Whi = S3;    hiP = true;  }
    else               { lo = t3;  Wlo = S3;  hi = mx; Whi = total; hiP = false; }

    // ---- 4 adaptive refinements (S-only), round-trips 2..5
    #pragma unroll
    for (int it = 0; it < 4; ++it) {
        float t;
        if (!hiP) {
            // proportional model through (lo, Wlo); clamps guarantee shrink
            t = fminf(lo * (wb / Wlo), lo + 0.90f * (hi - lo));
            t = fmaxf(t, lo + 0.08f * (hi - lo));
        } else {
            float fr = (wb - Wlo) / (Whi - Wlo);
            fr = fminf(fmaxf(fr, 0.06f), 0.94f);
            t = lo + (hi - lo) * fr;
        }
        float sv = 0.f;
        #pragma unroll
        for (int k = 0; k < PER_LANE; ++k)
            sv += (d2[k] <= t) ? w[k] : 0.f;
        const float s = wave_sum1(sv);
        if (s >= wb) { hi = t; Whi = s; hiP = true; }
        else         { lo = t; Wlo = s; }
    }

    // ---- two-sided epilogue: A at lo and hi in one pass (round-trip 6)
    float Alv = 0.f, Ahv = 0.f;
    #pragma unroll
    for (int k = 0; k < PER_LANE; ++k) {
        const float dk = d2[k];
        const float dw = dk * w[k];
        Ahv += (dk < hi) ? dw : 0.f;
        Alv += (dk < lo) ? dw : 0.f;
    }
    wave_sum2_u(Alv, Ahv);

    // concave-envelope estimate (S at endpoints = Wlo/Whi from the search)
    float val;
    if (hiP) {
        float that = (Ahv - Alv) / (Whi - Wlo);      // Whi>=wb>Wlo => >0
        that = fminf(fmaxf(that, lo), hi);
        const float vL   = Alv + that * (wb - Wlo);  // tangent from lo
        const float vH   = Ahv + that * (wb - Whi);  // tangent from hi
        const float vhat = fminf(vL, vH);            // upper bound, wb*val
        const float vmax = fmaxf(Alv + lo * (wb - Wlo),
                                 Ahv + hi * (wb - Whi));   // lower bound
        val = 0.5f * (vhat + vmax) / wb;
    } else {                                          // never bracketed (rare)
        val = (Alv + 0.5f * (lo + hi) * (wb - Wlo)) / wb;
    }

    if (lane == 0) out[q] = sqrtf(fmaxf(val, 0.f));
}

extern "C" void kernel_launch(void* const* d_in, const int* in_sizes, int n_in,
                              void* d_out, int out_size, void* d_ws, size_t ws_size,
                              hipStream_t stream) {
    const float* input  = (const float*)d_in[0];   // [32,1024,2]
    const float* weight = (const float*)d_in[1];   // [32,1024]
    const float* grid   = (const float*)d_in[2];   // [1024,2]
    float* out = (float*)d_out;                    // [32,1024]

    const int total_q = 32 * 1024;                 // B*N
    dim3 blk(256);                                 // 4 waves/block, 1 query/wave
    dim3 grd(total_q / 4);                         // 8192 blocks
    hipLaunchKernelGGL(dtm_kernel, grd, blk, 0, stream,
                       input, weight, grid, out);
}

// Round 14
// 43.949 us; speedup vs baseline: 1.0714x; 1.0714x over previous
//
#include <hip/hip_runtime.h>
#include <math.h>

// DTM layer: B=32, N=1024, D=2, M0=0.05, R=2
// out = sqrt( (A_strict(t*) + t*(wb - S_strict(t*)))/wb ), t* = weighted
// 5%-quantile of d2, wb = 0.05*sum_b(w).
// R12: per-wave INTEGER LDS histogram for bracketing (R1 redux done right:
// ds_add_u32 is native & hardware-serialized; R1's failure was FLOAT LDS
// atomicAdd -> divergent CAS-retry loop). 64 quarter-octave buckets on the
// d2 bit pattern; fixed-point weights (x2^20). One DPP u32 inclusive scan +
// ballot picks the bucket (bracket ratio 1.19); 2 interpolative fp32 refines;
// R8's proven two-sided fp32 epilogue (A,S at lo & hi; concave-envelope:
// val(t) is concave piecewise-linear, max at t*; tangent intersection exact
// when <=1 point inside the final bracket).
// Cuts: no exp seed, no mx reduction, no wsum reduction (= histogram total),
// no ladder scans. Source instr ~610 vs R11's ~820.

constexpr int      PER_LANE   = 16;        // 1024 / 64
constexpr float    M0_        = 0.05f;
constexpr unsigned BUCKET_OFF = 476u;      // (bits>>21)-476: bucket 0 at d2=2^-8
constexpr float    WSCALE     = 1048576.0f;    // 2^20
constexpr float    WINV       = 9.5367431640625e-07f;  // 2^-20

template<int CTRL, int RM>
__device__ __forceinline__ unsigned dpp_uadd(unsigned v) {
    unsigned m = (unsigned)__builtin_amdgcn_update_dpp(0, (int)v, CTRL, RM, 0xF, true);
    return v + m;
}
template<int CTRL, int RM>
__device__ __forceinline__ float dpp_fadd(float v) {
    int m = __builtin_amdgcn_update_dpp(0, __float_as_int(v), CTRL, RM, 0xF, true);
    return v + __int_as_float(m);
}
__device__ __forceinline__ float lane63f(float v) {
    return __uint_as_float((unsigned)__builtin_amdgcn_readlane(__float_as_int(v), 63));
}

// u32 inclusive prefix scan across 64 lanes (classic row_shr + row_bcast)
__device__ __forceinline__ unsigned wave_scan_u32(unsigned v) {
    v = dpp_uadd<0x111,0xF>(v);    // row_shr:1
    v = dpp_uadd<0x112,0xF>(v);    // row_shr:2
    v = dpp_uadd<0x114,0xF>(v);    // row_shr:4
    v = dpp_uadd<0x118,0xF>(v);    // row_shr:8
    v = dpp_uadd<0x142,0xA>(v);    // row_bcast:15 -> rows 1,3
    v = dpp_uadd<0x143,0xC>(v);    // row_bcast:31 -> rows 2,3
    return v;                      // lane63 = total
}
// full-wave float sum -> wave-uniform scalar
__device__ __forceinline__ float wave_sum1(float v) {
    v = dpp_fadd<0x111,0xF>(v); v = dpp_fadd<0x112,0xF>(v);
    v = dpp_fadd<0x114,0xF>(v); v = dpp_fadd<0x118,0xF>(v);
    v = dpp_fadd<0x142,0xA>(v); v = dpp_fadd<0x143,0xC>(v);
    return lane63f(v);
}
// four interleaved float sums (latency overlap)
__device__ __forceinline__ void wave_sum4_u(float& a, float& b, float& c, float& d) {
#define STG(CT, RM) \
    a = dpp_fadd<CT,RM>(a); b = dpp_fadd<CT,RM>(b); \
    c = dpp_fadd<CT,RM>(c); d = dpp_fadd<CT,RM>(d);
    STG(0x111,0xF) STG(0x112,0xF) STG(0x114,0xF)
    STG(0x118,0xF) STG(0x142,0xA) STG(0x143,0xC)
#undef STG
    a = lane63f(a); b = lane63f(b); c = lane63f(c); d = lane63f(d);
}

__global__ __launch_bounds__(256) void dtm_kernel(
    const float* __restrict__ input,   // [B, N, 2]
    const float* __restrict__ weight,  // [B, N]
    const float* __restrict__ grid,    // [N, 2]
    float* __restrict__ out)           // [B, N]
{
    __shared__ unsigned hist[4][64];   // per-wave private rows -> no barriers
    const int wave = threadIdx.x >> 6;
    const int lane = threadIdx.x & 63;
    const int q    = (blockIdx.x << 2) + wave;
    const int b    = q >> 10;

    const float2 xq = reinterpret_cast<const float2*>(input)[q];

    hist[wave][lane] = 0u;             // whole-wave zero, program order

    const int base = lane * PER_LANE;
    const float4* w4 = reinterpret_cast<const float4*>(weight + (b << 10) + base);
    const float4* g4 = reinterpret_cast<const float4*>(grid + 2 * base);

    float w[PER_LANE], d2[PER_LANE];
    #pragma unroll
    for (int i = 0; i < 4; ++i) {
        const float4 x = w4[i];
        w[4*i+0] = x.x; w[4*i+1] = x.y; w[4*i+2] = x.z; w[4*i+3] = x.w;
    }

    // ---- pass0: d2 + fixed-point histogram (bucket = quarter-octave of d2)
    unsigned* hrow = hist[wave];
    #pragma unroll
    for (int i = 0; i < 8; ++i) {                   // 2 grid points per float4
        const float4 g = g4[i];
        #pragma unroll
        for (int j = 0; j < 2; ++j) {
            const int k  = 2*i + j;
            const float gx = j ? g.z : g.x;
            const float gy = j ? g.w : g.y;
            const float dx = xq.x - gx, dy = xq.y - gy;
            const float dk = dx * dx + dy * dy;
            d2[k] = dk;
            int ib = (int)(__float_as_uint(dk) >> 21) - (int)BUCKET_OFF;
            ib = min(max(ib, 0), 63);
            const unsigned wi = (unsigned)(w[k] * WSCALE);
            atomicAdd(&hrow[ib], wi);               // native ds_add_u32
        }
    }

    // ---- bucket selection: one scan + ballot (round-trip 1)
    const unsigned h   = hrow[lane];                // wave-private, no barrier
    const unsigned cum = wave_scan_u32(h);
    const unsigned totI = (unsigned)__builtin_amdgcn_readlane((int)cum, 63);
    const float    totF = (float)totI;
    const float    wb   = M0_ * totF * WINV;        // float weight bound
    const unsigned wbI  = (unsigned)(M0_ * totF);   // fixed-point bound

    const unsigned long long m = __ballot(cum >= wbI);
    const int s = (int)__ffsll(m) - 1;              // first bucket reaching wb

    const unsigned cumS = (unsigned)__builtin_amdgcn_readlane((int)cum, s);
    const unsigned hS   = (unsigned)__builtin_amdgcn_readlane((int)h,   s);

    // bracket: bucket s edges (s==0 collapses to [0, edge1) incl. clamp mass)
    float lo  = (s == 0) ? 0.f : __uint_as_float(((unsigned)s + BUCKET_OFF) << 21);
    float hi  = __uint_as_float(((unsigned)s + 1u + BUCKET_OFF) << 21);
    float Wlo = (s == 0) ? 0.f : (float)(cumS - hS) * WINV;
    float Whi = (float)cumS * WINV;

    // ---- 2 interpolative fp32 refines (round-trips 2,3)
    #pragma unroll
    for (int it = 0; it < 2; ++it) {
        float fr = (wb - Wlo) / (Whi - Wlo);
        fr = fminf(fmaxf(fr, 0.06f), 0.94f);
        const float t = lo + (hi - lo) * fr;
        float sv = 0.f;
        #pragma unroll
        for (int k = 0; k < PER_LANE; ++k)
            sv += (d2[k] <= t) ? w[k] : 0.f;
        const float sw = wave_sum1(sv);
        if (sw >= wb) { hi = t; Whi = sw; }
        else          { lo = t; Wlo = sw; }
    }

    // ---- two-sided fp32 epilogue: A,S at lo and hi (round-trip 4)
    float Al = 0.f, Sl = 0.f, Ah = 0.f, Sh = 0.f;
    #pragma unroll
    for (int k = 0; k < PER_LANE; ++k) {
        const float dk = d2[k];
        const float wk = w[k];
        const float dw = dk * wk;
        const bool ih = (dk < hi);
        const bool il = (dk < lo);
        Ah += ih ? dw : 0.f;  Sh += ih ? wk : 0.f;
        Al += il ? dw : 0.f;  Sl += il ? wk : 0.f;
    }
    wave_sum4_u(Al, Sl, Ah, Sh);

    // concave-envelope estimate (R8 formula, consistent fp32 pairs)
    const float dS = Sh - Sl;
    float that = (dS > 0.f) ? (Ah - Al) / dS : hi;
    that = fminf(fmaxf(that, lo), hi);
    const float vL   = Al + that * (wb - Sl);        // tangent from lo
    const float vH   = Ah + that * (wb - Sh);        // tangent from hi
    const float vhat = fminf(vL, vH);                // upper bound on wb*val
    const float vmax = fmaxf(Al + lo * (wb - Sl),
                             Ah + hi * (wb - Sh));   // lower bound
    const float val  = 0.5f * (vhat + vmax) / wb;

    if (lane == 0) out[q] = sqrtf(fmaxf(val, 0.f));
}

extern "C" void kernel_launch(void* const* d_in, const int* in_sizes, int n_in,
                              void* d_out, int out_size, void* d_ws, size_t ws_size,
                              hipStream_t stream) {
    const float* input  = (const float*)d_in[0];   // [32,1024,2]
    const float* weight = (const float*)d_in[1];   // [32,1024]
    const float* grid   = (const float*)d_in[2];   // [1024,2]
    float* out = (float*)d_out;                    // [32,1024]

    const int total_q = 32 * 1024;                 // B*N
    dim3 blk(256);                                 // 4 waves/block, 1 query/wave
    dim3 grd(total_q / 4);                         // 8192 blocks
    hipLaunchKernelGGL(dtm_kernel, grd, blk, 0, stream,
                       input, weight, grid, out);
}